// Round 5
// baseline (2317.760 us; speedup 1.0000x reference)
//
#include <hip/hip_runtime.h>
#include <hip/hip_bf16.h>
#include <stdint.h>

// ---------- types ----------
typedef unsigned short u16;
typedef __bf16 bf16x8 __attribute__((ext_vector_type(8)));
typedef u16   u16x8  __attribute__((ext_vector_type(8)));
typedef u16   u16x4  __attribute__((ext_vector_type(4)));
typedef u16   u16x2  __attribute__((ext_vector_type(2)));
typedef float f32x4  __attribute__((ext_vector_type(4)));

__device__ __forceinline__ u16 f2bf(float f) {
  union { float f; uint32_t u; } v; v.f = f;
  uint32_t r = v.u + 0x7fffu + ((v.u >> 16) & 1u);   // RNE
  return (u16)(r >> 16);
}

// async global->LDS, 16B per lane
typedef __attribute__((address_space(1))) void gvoid_t;
typedef __attribute__((address_space(3))) void lvoid_t;
__device__ __forceinline__ void gload_lds16(const void* g, void* l) {
  __builtin_amdgcn_global_load_lds((gvoid_t*)g, (lvoid_t*)l, 16, 0, 0);
}

// ---------- DPP row(16-lane) reductions — VALU pipe, no DS ----------
template<int CTRL>
__device__ __forceinline__ float dpp_f(float x) {
  int i = __builtin_bit_cast(int, x);
  i = __builtin_amdgcn_update_dpp(i, i, CTRL, 0xF, 0xF, true);
  return __builtin_bit_cast(float, i);
}
__device__ __forceinline__ float rowmax16(float x) {   // ROW_ROR 8,4,2,1
  x = fmaxf(x, dpp_f<0x128>(x));
  x = fmaxf(x, dpp_f<0x124>(x));
  x = fmaxf(x, dpp_f<0x122>(x));
  x = fmaxf(x, dpp_f<0x121>(x));
  return x;
}
__device__ __forceinline__ float rowsum16(float x) {
  x += dpp_f<0x128>(x);
  x += dpp_f<0x124>(x);
  x += dpp_f<0x122>(x);
  x += dpp_f<0x121>(x);
  return x;
}

// ---------- LayerNorm (f32 in -> bf16 out), 1024 cols, one row per block ----------
__global__ __launch_bounds__(256)
void ln_kernel(const float* __restrict__ x, const float* __restrict__ g,
               const float* __restrict__ b, u16* __restrict__ out) {
  const int row = blockIdx.x;
  const int tid = threadIdx.x;
  const float* xr = x + (size_t)row * 1024;
  f32x4 v = *(const f32x4*)&xr[tid * 4];
  float s = v[0] + v[1] + v[2] + v[3];
  float q = v[0]*v[0] + v[1]*v[1] + v[2]*v[2] + v[3]*v[3];
  #pragma unroll
  for (int o = 32; o > 0; o >>= 1) { s += __shfl_xor(s, o); q += __shfl_xor(q, o); }
  __shared__ float ss[4], qq[4];
  if ((tid & 63) == 0) { ss[tid >> 6] = s; qq[tid >> 6] = q; }
  __syncthreads();
  s = ss[0] + ss[1] + ss[2] + ss[3];
  q = qq[0] + qq[1] + qq[2] + qq[3];
  float mu = s * (1.0f / 1024.0f);
  float var = q * (1.0f / 1024.0f) - mu * mu;
  float rstd = rsqrtf(var + 1e-5f);
  u16x4 o4;
  #pragma unroll
  for (int i = 0; i < 4; ++i)
    o4[i] = f2bf((v[i] - mu) * rstd * g[tid * 4 + i] + b[tid * 4 + i]);
  *(u16x4*)&out[(size_t)row * 1024 + tid * 4] = o4;
}

// ---------- transpose + cast: W f32 [K][N] -> Wt bf16 [N][K] ----------
__global__ __launch_bounds__(256)
void transpose_cast(const float* __restrict__ W, u16* __restrict__ Wt, int K, int N) {
  __shared__ float t[32][33];
  const int n0 = blockIdx.x * 32, k0 = blockIdx.y * 32;
  const int tx = threadIdx.x & 31, ty = threadIdx.x >> 5;  // ty 0..7
  #pragma unroll
  for (int i = 0; i < 4; ++i)
    t[ty + 8*i][tx] = W[(size_t)(k0 + ty + 8*i) * N + n0 + tx];
  __syncthreads();
  #pragma unroll
  for (int i = 0; i < 4; ++i)
    Wt[(size_t)(n0 + ty + 8*i) * K + k0 + tx] = f2bf(t[tx][ty + 8*i]);
}

// ---------- GEMM: C[M][N] = A[M][K] @ Bt[N][K]^T  (both bf16, f32 accum) ----------
template<int EPI>
__global__ __launch_bounds__(256, 2)
void gemm_bt(const u16* __restrict__ A, const u16* __restrict__ Bt,
             void* __restrict__ out, const float* __restrict__ bias,
             const float* __restrict__ resid, int M, int N, int K) {
  __shared__ u16 As[128 * 32];
  __shared__ u16 Bs[128 * 32];
  const int tid = threadIdx.x;
  const int w = tid >> 6, l = tid & 63;
  const int bm = blockIdx.x * 128, bn = blockIdx.y * 128;
  const int wr = (w >> 1) * 64, wc = (w & 1) * 64;
  const int l15 = l & 15, lhi = l >> 4;
  f32x4 acc[4][4] = {};

  const int r4 = tid >> 2;
  const int c8 = (tid & 3) * 8;
  const u16* ga0 = A  + (size_t)(bm + r4) * K + c8;
  const u16* ga1 = ga0 + (size_t)64 * K;
  const u16* gb0 = Bt + (size_t)(bn + r4) * K + c8;
  const u16* gb1 = gb0 + (size_t)64 * K;
  u16* lA0 = &As[(w * 16) * 32];
  u16* lA1 = &As[(64 + w * 16) * 32];
  u16* lB0 = &Bs[(w * 16) * 32];
  u16* lB1 = &Bs[(64 + w * 16) * 32];

  const int arow = (wr + l15) * 32 + lhi * 8;
  const int brow = (wc + l15) * 32 + lhi * 8;

  for (int k0 = 0; k0 < K; k0 += 32) {
    gload_lds16(ga0 + k0, lA0);
    gload_lds16(ga1 + k0, lA1);
    gload_lds16(gb0 + k0, lB0);
    gload_lds16(gb1 + k0, lB1);
    __syncthreads();
    bf16x8 a[4], b[4];
    #pragma unroll
    for (int m = 0; m < 4; ++m) a[m] = *(const bf16x8*)&As[arow + m * 16 * 32];
    #pragma unroll
    for (int n = 0; n < 4; ++n) b[n] = *(const bf16x8*)&Bs[brow + n * 16 * 32];
    #pragma unroll
    for (int m = 0; m < 4; ++m)
      #pragma unroll
      for (int n = 0; n < 4; ++n)
        acc[m][n] = __builtin_amdgcn_mfma_f32_16x16x32_bf16(a[m], b[n], acc[m][n], 0, 0, 0);
    __syncthreads();
  }

  #pragma unroll
  for (int m = 0; m < 4; ++m) {
    #pragma unroll
    for (int n = 0; n < 4; ++n) {
      #pragma unroll
      for (int r = 0; r < 4; ++r) {
        const int grow = bm + wr + m * 16 + lhi * 4 + r;
        const int gcol = bn + wc + n * 16 + l15;
        float vv = acc[m][n][r];
        if constexpr (EPI >= 1) vv += bias[gcol];
        if constexpr (EPI == 1) vv = 0.5f * vv * (1.0f + erff(vv * 0.70710678118f));
        if constexpr (EPI == 2) {
          vv += resid[(size_t)grow * N + gcol];
          ((float*)out)[(size_t)grow * N + gcol] = vv;
        } else {
          ((u16*)out)[(size_t)grow * N + gcol] = f2bf(vv);
        }
      }
    }
  }
}

// ---------- fused flash attention v5 ----------
// R0 shape (grid 32x32, 256 thr / 4 waves, one batch-head per block) +
// reg-prefetch of K/V one iter ahead (write-late), bias prefetched into RAW
// f32 regs (no packing -> vmcnt wait lands at use, next iter), DPP softmax
// (log2 domain, defer-max), XOR-swizzled stride-64 LDS (24KB), 2 barriers/iter.
// qkv: bf16 [B*S][3072]; bias: f32 [H][S][S]; ctx: bf16 [B*S][1024]
#define SWZ(row) ((((row) & 7) ^ (((row) >> 3) & 7)) << 3)

__global__ __launch_bounds__(256, 4)
void attn_kernel(const u16* __restrict__ qkv, const float* __restrict__ bias,
                 u16* __restrict__ ctx) {
  const int qt = blockIdx.x;            // 0..31 (64 q-rows)
  const int bh = blockIdx.y;            // 0..31
  const int b = bh >> 4, h = bh & 15;
  const int tid = threadIdx.x, w = tid >> 6, l = tid & 63;
  const int l15 = l & 15, lhi = l >> 4;
  const size_t ld = 3072;
  const float L2E = 1.44269504f;

  __shared__ u16 Kl[4096];              // [key][64] swizzled
  __shared__ u16 Vt[4096];              // [d][64] (V^T) swizzled
  __shared__ u16 Pl[4][1024];           // per wave [qrow16][64] swizzled

  const u16* qp = qkv;
  const u16* kp = qkv + 1024;
  const u16* vp = qkv + 2048;

  // staging shard: key2 = 2 consecutive keys, dg8 = 8 d-elems
  const int key2 = (tid >> 3) * 2, dg8 = (tid & 7) * 8;
  const u16* kbase = kp + ((size_t)b * 2048 + key2) * ld + h * 64 + dg8;
  const u16* vbase = vp + ((size_t)b * 2048 + key2) * ld + h * 64 + dg8;

  // Q fragments: 16 q-rows per wave
  bf16x8 qf0, qf1;
  {
    const u16* qrow = qp + ((size_t)b * 2048 + qt * 64 + w * 16 + l15) * ld + h * 64 + lhi * 8;
    qf0 = *(const bf16x8*)qrow;
    qf1 = *(const bf16x8*)(qrow + 32);
  }

  const float* bg0 = bias + ((size_t)h * 2048 + qt * 64 + w * 16 + lhi * 4) * 2048 + l15;

  float m_run[4], s_run[4];
  f32x4 octx[4] = {};
  #pragma unroll
  for (int r = 0; r < 4; ++r) { m_run[r] = -1e30f; s_run[r] = 0.f; }

  u16x8 kpf[2], vpf[2];
  float bfA[16], bfB[16];               // raw f32 bias regs (no packing!)

  auto load_kv = [&](int kv) {
    kpf[0] = *(const u16x8*)(kbase + (size_t)kv * ld);
    kpf[1] = *(const u16x8*)(kbase + (size_t)(kv + 1) * ld);
    vpf[0] = *(const u16x8*)(vbase + (size_t)kv * ld);
    vpf[1] = *(const u16x8*)(vbase + (size_t)(kv + 1) * ld);
  };
  auto load_bias = [&](int kv, float (&bf)[16]) {
    #pragma unroll
    for (int r = 0; r < 4; ++r)
      #pragma unroll
      for (int nf = 0; nf < 4; ++nf)
        bf[r * 4 + nf] = bg0[(size_t)r * 2048 + kv + nf * 16];   // raw load, no VALU
  };
  auto store_kv = [&]() {
    *(u16x8*)&Kl[(key2)     * 64 + (dg8 ^ SWZ(key2))]     = kpf[0];
    *(u16x8*)&Kl[(key2 + 1) * 64 + (dg8 ^ SWZ(key2 + 1))] = kpf[1];
    #pragma unroll
    for (int i = 0; i < 8; ++i) {
      const int d = dg8 + i;
      u16x2 vq = { vpf[0][i], vpf[1][i] };
      *(u16x2*)&Vt[d * 64 + (key2 ^ SWZ(d))] = vq;
    }
  };

  // ---- prologue: tile 0 ----
  load_kv(0);
  load_bias(0, bfA);
  store_kv();
  __syncthreads();

  auto iter = [&](int it, float (&bc)[16], float (&bn)[16]) {
    const int kv0 = it * 64;
    const bool pf = it < 31;
    if (pf) { load_kv(kv0 + 64); load_bias(kv0 + 64, bn); }

    // ---- QK^T ----
    f32x4 sa[4] = {};
    #pragma unroll
    for (int nf = 0; nf < 4; ++nf) {
      const int row = nf * 16 + l15;
      const int s = SWZ(row);
      bf16x8 kf0 = *(const bf16x8*)&Kl[row * 64 + ((lhi * 8) ^ s)];
      bf16x8 kf1 = *(const bf16x8*)&Kl[row * 64 + ((32 + lhi * 8) ^ s)];
      sa[nf] = __builtin_amdgcn_mfma_f32_16x16x32_bf16(qf0, kf0, sa[nf], 0, 0, 0);
      sa[nf] = __builtin_amdgcn_mfma_f32_16x16x32_bf16(qf1, kf1, sa[nf], 0, 0, 0);
    }

    // ---- softmax (natural-units max, log2 exp; defer-max; DPP reductions) ----
    float p[4][4];
    #pragma unroll
    for (int r = 0; r < 4; ++r)
      #pragma unroll
      for (int nf = 0; nf < 4; ++nf)
        p[r][nf] = fmaf(sa[nf][r], 0.125f, bc[r * 4 + nf]);
    #pragma unroll
    for (int r = 0; r < 4; ++r) {
      float mx = fmaxf(fmaxf(p[r][0], p[r][1]), fmaxf(p[r][2], p[r][3]));
      mx = rowmax16(mx);
      if (mx > m_run[r] + 5.545177f) {       // 8 in log2 units
        const float fs = exp2f((m_run[r] - mx) * L2E);
        s_run[r] *= fs;
        #pragma unroll
        for (int nf = 0; nf < 4; ++nf) octx[nf][r] *= fs;
        m_run[r] = mx;
      }
      const float nml = -m_run[r] * L2E;
      float e0 = exp2f(fmaf(p[r][0], L2E, nml));
      float e1 = exp2f(fmaf(p[r][1], L2E, nml));
      float e2 = exp2f(fmaf(p[r][2], L2E, nml));
      float e3 = exp2f(fmaf(p[r][3], L2E, nml));
      p[r][0] = e0; p[r][1] = e1; p[r][2] = e2; p[r][3] = e3;
      s_run[r] += rowsum16((e0 + e1) + (e2 + e3));
    }

    // ---- P -> per-wave LDS (same-wave ordering, no barrier) ----
    #pragma unroll
    for (int r = 0; r < 4; ++r) {
      const int row = lhi * 4 + r;
      const int s = SWZ(row);
      #pragma unroll
      for (int nf = 0; nf < 4; ++nf)
        Pl[w][row * 64 + ((nf * 16 + l15) ^ s)] = f2bf(p[r][nf]);
    }

    // ---- PV ----
    #pragma unroll
    for (int ks = 0; ks < 2; ++ks) {
      bf16x8 pa = *(const bf16x8*)&Pl[w][l15 * 64 + ((ks * 32 + lhi * 8) ^ SWZ(l15))];
      #pragma unroll
      for (int nf = 0; nf < 4; ++nf) {
        const int row = nf * 16 + l15;
        bf16x8 bv = *(const bf16x8*)&Vt[row * 64 + ((ks * 32 + lhi * 8) ^ SWZ(row))];
        octx[nf] = __builtin_amdgcn_mfma_f32_16x16x32_bf16(pa, bv, octx[nf], 0, 0, 0);
      }
    }

    __syncthreads();              // all waves done reading tile it
    if (pf) store_kv();           // write prefetched tile it+1
    __syncthreads();              // tile it+1 visible
  };

  for (int it2 = 0; it2 < 16; ++it2) {
    iter(2 * it2,     bfA, bfB);
    iter(2 * it2 + 1, bfB, bfA);
  }

  // ---- normalize + write ctx ----
  float inv[4];
  #pragma unroll
  for (int r = 0; r < 4; ++r) inv[r] = 1.0f / s_run[r];
  #pragma unroll
  for (int nf = 0; nf < 4; ++nf)
    #pragma unroll
    for (int r = 0; r < 4; ++r) {
      const int grow = b * 2048 + qt * 64 + w * 16 + lhi * 4 + r;
      const int gcol = h * 64 + nf * 16 + l15;
      ctx[(size_t)grow * 1024 + gcol] = f2bf(octx[nf][r] * inv[r]);
    }
}

// ---------- launch ----------
extern "C" void kernel_launch(void* const* d_in, const int* in_sizes, int n_in,
                              void* d_out, int out_size, void* d_ws, size_t ws_size,
                              hipStream_t stream) {
  const float* x    = (const float*)d_in[0];
  const float* rb   = (const float*)d_in[1];
  const float* wq   = (const float*)d_in[2];
  const float* wk   = (const float*)d_in[3];
  const float* wv   = (const float*)d_in[4];
  const float* wo   = (const float*)d_in[5];
  const float* wo_b = (const float*)d_in[6];
  const float* w1   = (const float*)d_in[7];
  const float* b1   = (const float*)d_in[8];
  const float* w2   = (const float*)d_in[9];
  const float* b2   = (const float*)d_in[10];
  const float* ln1g = (const float*)d_in[11];
  const float* ln1b = (const float*)d_in[12];
  const float* ln2g = (const float*)d_in[13];
  const float* ln2b = (const float*)d_in[14];

  char* ws = (char*)d_ws;
  u16*   xn    = (u16*)(ws + 0);                    //  8 MB
  u16*   qkvb  = (u16*)(ws + (8u << 20));           // 24 MB
  u16*   hbuf  = (u16*)(ws + (8u << 20));           // 32 MB (reuses qkv+ctx)
  u16*   ctxb  = (u16*)(ws + (32u << 20));          //  8 MB
  float* x1    = (float*)(ws + (40u << 20));        // 16 MB
  u16*   wqkvt = (u16*)(ws + (56u << 20));          //  6 MB
  u16*   wot   = (u16*)(ws + (62u << 20));          //  2 MB
  u16*   w1t   = (u16*)(ws + (64u << 20));          //  8 MB
  u16*   w2t   = (u16*)(ws + (72u << 20));          //  8 MB

  transpose_cast<<<dim3(32, 32),  256, 0, stream>>>(wq, wqkvt,               1024, 1024);
  transpose_cast<<<dim3(32, 32),  256, 0, stream>>>(wk, wqkvt + 1024 * 1024, 1024, 1024);
  transpose_cast<<<dim3(32, 32),  256, 0, stream>>>(wv, wqkvt + 2048 * 1024, 1024, 1024);
  transpose_cast<<<dim3(32, 32),  256, 0, stream>>>(wo, wot,                 1024, 1024);
  transpose_cast<<<dim3(128, 32), 256, 0, stream>>>(w1, w1t,                 1024, 4096);
  transpose_cast<<<dim3(32, 128), 256, 0, stream>>>(w2, w2t,                 4096, 1024);

  ln_kernel<<<4096, 256, 0, stream>>>(x, ln1g, ln1b, xn);
  gemm_bt<0><<<dim3(32, 24), 256, 0, stream>>>(xn, wqkvt, qkvb, nullptr, nullptr, 4096, 3072, 1024);
  attn_kernel<<<dim3(32, 32), 256, 0, stream>>>(qkvb, rb, ctxb);
  gemm_bt<2><<<dim3(32, 8), 256, 0, stream>>>(ctxb, wot, x1, wo_b, x, 4096, 1024, 1024);
  ln_kernel<<<4096, 256, 0, stream>>>(x1, ln2g, ln2b, xn);
  gemm_bt<1><<<dim3(32, 32), 256, 0, stream>>>(xn, w1t, hbuf, b1, nullptr, 4096, 4096, 1024);
  gemm_bt<2><<<dim3(32, 8), 256, 0, stream>>>(hbuf, w2t, (float*)d_out, b2, x1, 4096, 1024, 4096);

  (void)in_sizes; (void)n_in; (void)out_size; (void)ws_size;
}

// Round 6
// 402.174 us; speedup vs baseline: 5.7631x; 5.7631x over previous
//
#include <hip/hip_runtime.h>
#include <hip/hip_bf16.h>
#include <stdint.h>

// ---------- types ----------
typedef unsigned short u16;
typedef __bf16 bf16x8 __attribute__((ext_vector_type(8)));
typedef u16   u16x8  __attribute__((ext_vector_type(8)));
typedef u16   u16x4  __attribute__((ext_vector_type(4)));
typedef u16   u16x2  __attribute__((ext_vector_type(2)));
typedef float f32x4  __attribute__((ext_vector_type(4)));

__device__ __forceinline__ u16 f2bf(float f) {
  union { float f; uint32_t u; } v; v.f = f;
  uint32_t r = v.u + 0x7fffu + ((v.u >> 16) & 1u);   // RNE
  return (u16)(r >> 16);
}

// async global->LDS, 16B per lane
typedef __attribute__((address_space(1))) void gvoid_t;
typedef __attribute__((address_space(3))) void lvoid_t;
__device__ __forceinline__ void gload_lds16(const void* g, void* l) {
  __builtin_amdgcn_global_load_lds((gvoid_t*)g, (lvoid_t*)l, 16, 0, 0);
}

// ---------- DPP row(16-lane) reductions — VALU pipe, no DS ----------
template<int CTRL>
__device__ __forceinline__ float dpp_f(float x) {
  int i = __builtin_bit_cast(int, x);
  i = __builtin_amdgcn_update_dpp(i, i, CTRL, 0xF, 0xF, true);
  return __builtin_bit_cast(float, i);
}
__device__ __forceinline__ float rowmax16(float x) {   // ROW_ROR 8,4,2,1
  x = fmaxf(x, dpp_f<0x128>(x));
  x = fmaxf(x, dpp_f<0x124>(x));
  x = fmaxf(x, dpp_f<0x122>(x));
  x = fmaxf(x, dpp_f<0x121>(x));
  return x;
}
__device__ __forceinline__ float rowsum16(float x) {
  x += dpp_f<0x128>(x);
  x += dpp_f<0x124>(x);
  x += dpp_f<0x122>(x);
  x += dpp_f<0x121>(x);
  return x;
}

// ---------- LayerNorm (f32 in -> bf16 out), 1024 cols, one row per block ----------
__global__ __launch_bounds__(256)
void ln_kernel(const float* __restrict__ x, const float* __restrict__ g,
               const float* __restrict__ b, u16* __restrict__ out) {
  const int row = blockIdx.x;
  const int tid = threadIdx.x;
  const float* xr = x + (size_t)row * 1024;
  f32x4 v = *(const f32x4*)&xr[tid * 4];
  float s = v[0] + v[1] + v[2] + v[3];
  float q = v[0]*v[0] + v[1]*v[1] + v[2]*v[2] + v[3]*v[3];
  #pragma unroll
  for (int o = 32; o > 0; o >>= 1) { s += __shfl_xor(s, o); q += __shfl_xor(q, o); }
  __shared__ float ss[4], qq[4];
  if ((tid & 63) == 0) { ss[tid >> 6] = s; qq[tid >> 6] = q; }
  __syncthreads();
  s = ss[0] + ss[1] + ss[2] + ss[3];
  q = qq[0] + qq[1] + qq[2] + qq[3];
  float mu = s * (1.0f / 1024.0f);
  float var = q * (1.0f / 1024.0f) - mu * mu;
  float rstd = rsqrtf(var + 1e-5f);
  u16x4 o4;
  #pragma unroll
  for (int i = 0; i < 4; ++i)
    o4[i] = f2bf((v[i] - mu) * rstd * g[tid * 4 + i] + b[tid * 4 + i]);
  *(u16x4*)&out[(size_t)row * 1024 + tid * 4] = o4;
}

// ---------- transpose + cast: W f32 [K][N] -> Wt bf16 [N][K] ----------
__global__ __launch_bounds__(256)
void transpose_cast(const float* __restrict__ W, u16* __restrict__ Wt, int K, int N) {
  __shared__ float t[32][33];
  const int n0 = blockIdx.x * 32, k0 = blockIdx.y * 32;
  const int tx = threadIdx.x & 31, ty = threadIdx.x >> 5;  // ty 0..7
  #pragma unroll
  for (int i = 0; i < 4; ++i)
    t[ty + 8*i][tx] = W[(size_t)(k0 + ty + 8*i) * N + n0 + tx];
  __syncthreads();
  #pragma unroll
  for (int i = 0; i < 4; ++i)
    Wt[(size_t)(n0 + ty + 8*i) * K + k0 + tx] = f2bf(t[tx][ty + 8*i]);
}

// ---------- GEMM: C[M][N] = A[M][K] @ Bt[N][K]^T  (both bf16, f32 accum) ----------
template<int EPI>
__global__ __launch_bounds__(256, 2)
void gemm_bt(const u16* __restrict__ A, const u16* __restrict__ Bt,
             void* __restrict__ out, const float* __restrict__ bias,
             const float* __restrict__ resid, int M, int N, int K) {
  __shared__ u16 As[128 * 32];
  __shared__ u16 Bs[128 * 32];
  const int tid = threadIdx.x;
  const int w = tid >> 6, l = tid & 63;
  const int bm = blockIdx.x * 128, bn = blockIdx.y * 128;
  const int wr = (w >> 1) * 64, wc = (w & 1) * 64;
  const int l15 = l & 15, lhi = l >> 4;
  f32x4 acc[4][4] = {};

  const int r4 = tid >> 2;
  const int c8 = (tid & 3) * 8;
  const u16* ga0 = A  + (size_t)(bm + r4) * K + c8;
  const u16* ga1 = ga0 + (size_t)64 * K;
  const u16* gb0 = Bt + (size_t)(bn + r4) * K + c8;
  const u16* gb1 = gb0 + (size_t)64 * K;
  u16* lA0 = &As[(w * 16) * 32];
  u16* lA1 = &As[(64 + w * 16) * 32];
  u16* lB0 = &Bs[(w * 16) * 32];
  u16* lB1 = &Bs[(64 + w * 16) * 32];

  const int arow = (wr + l15) * 32 + lhi * 8;
  const int brow = (wc + l15) * 32 + lhi * 8;

  for (int k0 = 0; k0 < K; k0 += 32) {
    gload_lds16(ga0 + k0, lA0);
    gload_lds16(ga1 + k0, lA1);
    gload_lds16(gb0 + k0, lB0);
    gload_lds16(gb1 + k0, lB1);
    __syncthreads();
    bf16x8 a[4], b[4];
    #pragma unroll
    for (int m = 0; m < 4; ++m) a[m] = *(const bf16x8*)&As[arow + m * 16 * 32];
    #pragma unroll
    for (int n = 0; n < 4; ++n) b[n] = *(const bf16x8*)&Bs[brow + n * 16 * 32];
    #pragma unroll
    for (int m = 0; m < 4; ++m)
      #pragma unroll
      for (int n = 0; n < 4; ++n)
        acc[m][n] = __builtin_amdgcn_mfma_f32_16x16x32_bf16(a[m], b[n], acc[m][n], 0, 0, 0);
    __syncthreads();
  }

  #pragma unroll
  for (int m = 0; m < 4; ++m) {
    #pragma unroll
    for (int n = 0; n < 4; ++n) {
      #pragma unroll
      for (int r = 0; r < 4; ++r) {
        const int grow = bm + wr + m * 16 + lhi * 4 + r;
        const int gcol = bn + wc + n * 16 + l15;
        float vv = acc[m][n][r];
        if constexpr (EPI >= 1) vv += bias[gcol];
        if constexpr (EPI == 1) vv = 0.5f * vv * (1.0f + erff(vv * 0.70710678118f));
        if constexpr (EPI == 2) {
          vv += resid[(size_t)grow * N + gcol];
          ((float*)out)[(size_t)grow * N + gcol] = vv;
        } else {
          ((u16*)out)[(size_t)grow * N + gcol] = f2bf(vv);
        }
      }
    }
  }
}

// ---------- fused flash attention v6 ----------
// R0 shape (grid 32x32, 256 thr / 4 waves, one batch-head per block).
// Single-buffer reg-prefetch of K/V (load top, LDS-store after barrier) and
// bias (16 raw f32; next-iter loads issued right AFTER current use -> full-iter
// latency window, no packing VALU). No launch_bounds min-waves: let the
// allocator take ~110-128 VGPRs, NO spills (R4's 4.2GB scratch traffic bug).
// DPP softmax (defer-max), XOR-swizzled stride-64 LDS (24KB), 2 barriers/iter.
// qkv: bf16 [B*S][3072]; bias: f32 [H][S][S]; ctx: bf16 [B*S][1024]
#define SWZ(row) ((((row) & 7) ^ (((row) >> 3) & 7)) << 3)

__global__ __launch_bounds__(256)
void attn_kernel(const u16* __restrict__ qkv, const float* __restrict__ bias,
                 u16* __restrict__ ctx) {
  const int qt = blockIdx.x;            // 0..31 (64 q-rows)
  const int bh = blockIdx.y;            // 0..31
  const int b = bh >> 4, h = bh & 15;
  const int tid = threadIdx.x, w = tid >> 6, l = tid & 63;
  const int l15 = l & 15, lhi = l >> 4;
  const size_t ld = 3072;
  const float L2E = 1.44269504f;

  __shared__ u16 Kl[4096];              // [key][64] swizzled
  __shared__ u16 Vt[4096];              // [d][64] (V^T) swizzled
  __shared__ u16 Pl[4][1024];           // per wave [qrow16][64] swizzled

  const u16* qp = qkv;
  const u16* kp = qkv + 1024;
  const u16* vp = qkv + 2048;

  // staging shard: key2 = 2 consecutive keys, dg8 = 8 d-elems
  const int key2 = (tid >> 3) * 2, dg8 = (tid & 7) * 8;
  const u16* kbase = kp + ((size_t)b * 2048 + key2) * ld + h * 64 + dg8;
  const u16* vbase = vp + ((size_t)b * 2048 + key2) * ld + h * 64 + dg8;

  // Q fragments: 16 q-rows per wave
  bf16x8 qf0, qf1;
  {
    const u16* qrow = qp + ((size_t)b * 2048 + qt * 64 + w * 16 + l15) * ld + h * 64 + lhi * 8;
    qf0 = *(const bf16x8*)qrow;
    qf1 = *(const bf16x8*)(qrow + 32);
  }

  const float* bg0 = bias + ((size_t)h * 2048 + qt * 64 + w * 16 + lhi * 4) * 2048 + l15;

  float m_run[4], s_run[4];
  f32x4 octx[4] = {};
  #pragma unroll
  for (int r = 0; r < 4; ++r) { m_run[r] = -1e30f; s_run[r] = 0.f; }

  u16x8 kpf[2], vpf[2];                 // single K/V prefetch buffer
  float bf[16];                         // single bias buffer, raw f32

  auto load_kv = [&](int kv) {
    kpf[0] = *(const u16x8*)(kbase + (size_t)kv * ld);
    kpf[1] = *(const u16x8*)(kbase + (size_t)(kv + 1) * ld);
    vpf[0] = *(const u16x8*)(vbase + (size_t)kv * ld);
    vpf[1] = *(const u16x8*)(vbase + (size_t)(kv + 1) * ld);
  };
  auto load_bias = [&](int kv) {
    #pragma unroll
    for (int r = 0; r < 4; ++r)
      #pragma unroll
      for (int nf = 0; nf < 4; ++nf)
        bf[r * 4 + nf] = bg0[(size_t)r * 2048 + kv + nf * 16];   // raw load, no VALU
  };
  auto store_kv = [&]() {
    *(u16x8*)&Kl[(key2)     * 64 + (dg8 ^ SWZ(key2))]     = kpf[0];
    *(u16x8*)&Kl[(key2 + 1) * 64 + (dg8 ^ SWZ(key2 + 1))] = kpf[1];
    #pragma unroll
    for (int i = 0; i < 8; ++i) {
      const int d = dg8 + i;
      u16x2 vq = { vpf[0][i], vpf[1][i] };
      *(u16x2*)&Vt[d * 64 + (key2 ^ SWZ(d))] = vq;
    }
  };

  // ---- prologue: tile 0 ----
  load_kv(0);
  load_bias(0);
  store_kv();
  __syncthreads();

  for (int it = 0; it < 32; ++it) {
    const int kv0 = it * 64;
    const bool pf = it < 31;
    if (pf) load_kv(kv0 + 64);          // K/V(it+1) -> regs (stored after barrier)

    // ---- QK^T ----
    f32x4 sa[4] = {};
    #pragma unroll
    for (int nf = 0; nf < 4; ++nf) {
      const int row = nf * 16 + l15;
      const int s = SWZ(row);
      bf16x8 kf0 = *(const bf16x8*)&Kl[row * 64 + ((lhi * 8) ^ s)];
      bf16x8 kf1 = *(const bf16x8*)&Kl[row * 64 + ((32 + lhi * 8) ^ s)];
      sa[nf] = __builtin_amdgcn_mfma_f32_16x16x32_bf16(qf0, kf0, sa[nf], 0, 0, 0);
      sa[nf] = __builtin_amdgcn_mfma_f32_16x16x32_bf16(qf1, kf1, sa[nf], 0, 0, 0);
    }

    // ---- consume bias, then immediately re-issue loads for it+1 ----
    float p[4][4];
    #pragma unroll
    for (int r = 0; r < 4; ++r)
      #pragma unroll
      for (int nf = 0; nf < 4; ++nf)
        p[r][nf] = fmaf(sa[nf][r], 0.125f, bf[r * 4 + nf]);
    if (pf) load_bias(kv0 + 64);        // full softmax+PV+QK window to land

    // ---- softmax (defer-max, DPP reductions, exp2) ----
    #pragma unroll
    for (int r = 0; r < 4; ++r) {
      float mx = fmaxf(fmaxf(p[r][0], p[r][1]), fmaxf(p[r][2], p[r][3]));
      mx = rowmax16(mx);
      if (mx > m_run[r] + 5.545177f) {       // 8 in log2 units
        const float fs = exp2f((m_run[r] - mx) * L2E);
        s_run[r] *= fs;
        #pragma unroll
        for (int nf = 0; nf < 4; ++nf) octx[nf][r] *= fs;
        m_run[r] = mx;
      }
      const float nml = -m_run[r] * L2E;
      float e0 = exp2f(fmaf(p[r][0], L2E, nml));
      float e1 = exp2f(fmaf(p[r][1], L2E, nml));
      float e2 = exp2f(fmaf(p[r][2], L2E, nml));
      float e3 = exp2f(fmaf(p[r][3], L2E, nml));
      p[r][0] = e0; p[r][1] = e1; p[r][2] = e2; p[r][3] = e3;
      s_run[r] += rowsum16((e0 + e1) + (e2 + e3));
    }

    // ---- P -> per-wave LDS (same-wave ordering, no barrier) ----
    #pragma unroll
    for (int r = 0; r < 4; ++r) {
      const int row = lhi * 4 + r;
      const int s = SWZ(row);
      #pragma unroll
      for (int nf = 0; nf < 4; ++nf)
        Pl[w][row * 64 + ((nf * 16 + l15) ^ s)] = f2bf(p[r][nf]);
    }

    // ---- PV ----
    #pragma unroll
    for (int ks = 0; ks < 2; ++ks) {
      bf16x8 pa = *(const bf16x8*)&Pl[w][l15 * 64 + ((ks * 32 + lhi * 8) ^ SWZ(l15))];
      #pragma unroll
      for (int nf = 0; nf < 4; ++nf) {
        const int row = nf * 16 + l15;
        bf16x8 bv = *(const bf16x8*)&Vt[row * 64 + ((ks * 32 + lhi * 8) ^ SWZ(row))];
        octx[nf] = __builtin_amdgcn_mfma_f32_16x16x32_bf16(pa, bv, octx[nf], 0, 0, 0);
      }
    }

    __syncthreads();              // all waves done reading tile it
    if (pf) store_kv();           // write prefetched tile it+1 (vmcnt wait covered by full iter)
    __syncthreads();              // tile it+1 visible
  }

  // ---- normalize + write ctx ----
  float inv[4];
  #pragma unroll
  for (int r = 0; r < 4; ++r) inv[r] = 1.0f / s_run[r];
  #pragma unroll
  for (int nf = 0; nf < 4; ++nf)
    #pragma unroll
    for (int r = 0; r < 4; ++r) {
      const int grow = b * 2048 + qt * 64 + w * 16 + lhi * 4 + r;
      const int gcol = h * 64 + nf * 16 + l15;
      ctx[(size_t)grow * 1024 + gcol] = f2bf(octx[nf][r] * inv[r]);
    }
}

// ---------- launch ----------
extern "C" void kernel_launch(void* const* d_in, const int* in_sizes, int n_in,
                              void* d_out, int out_size, void* d_ws, size_t ws_size,
                              hipStream_t stream) {
  const float* x    = (const float*)d_in[0];
  const float* rb   = (const float*)d_in[1];
  const float* wq   = (const float*)d_in[2];
  const float* wk   = (const float*)d_in[3];
  const float* wv   = (const float*)d_in[4];
  const float* wo   = (const float*)d_in[5];
  const float* wo_b = (const float*)d_in[6];
  const float* w1   = (const float*)d_in[7];
  const float* b1   = (const float*)d_in[8];
  const float* w2   = (const float*)d_in[9];
  const float* b2   = (const float*)d_in[10];
  const float* ln1g = (const float*)d_in[11];
  const float* ln1b = (const float*)d_in[12];
  const float* ln2g = (const float*)d_in[13];
  const float* ln2b = (const float*)d_in[14];

  char* ws = (char*)d_ws;
  u16*   xn    = (u16*)(ws + 0);                    //  8 MB
  u16*   qkvb  = (u16*)(ws + (8u << 20));           // 24 MB
  u16*   hbuf  = (u16*)(ws + (8u << 20));           // 32 MB (reuses qkv+ctx)
  u16*   ctxb  = (u16*)(ws + (32u << 20));          //  8 MB
  float* x1    = (float*)(ws + (40u << 20));        // 16 MB
  u16*   wqkvt = (u16*)(ws + (56u << 20));          //  6 MB
  u16*   wot   = (u16*)(ws + (62u << 20));          //  2 MB
  u16*   w1t   = (u16*)(ws + (64u << 20));          //  8 MB
  u16*   w2t   = (u16*)(ws + (72u << 20));          //  8 MB

  transpose_cast<<<dim3(32, 32),  256, 0, stream>>>(wq, wqkvt,               1024, 1024);
  transpose_cast<<<dim3(32, 32),  256, 0, stream>>>(wk, wqkvt + 1024 * 1024, 1024, 1024);
  transpose_cast<<<dim3(32, 32),  256, 0, stream>>>(wv, wqkvt + 2048 * 1024, 1024, 1024);
  transpose_cast<<<dim3(32, 32),  256, 0, stream>>>(wo, wot,                 1024, 1024);
  transpose_cast<<<dim3(128, 32), 256, 0, stream>>>(w1, w1t,                 1024, 4096);
  transpose_cast<<<dim3(32, 128), 256, 0, stream>>>(w2, w2t,                 4096, 1024);

  ln_kernel<<<4096, 256, 0, stream>>>(x, ln1g, ln1b, xn);
  gemm_bt<0><<<dim3(32, 24), 256, 0, stream>>>(xn, wqkvt, qkvb, nullptr, nullptr, 4096, 3072, 1024);
  attn_kernel<<<dim3(32, 32), 256, 0, stream>>>(qkvb, rb, ctxb);
  gemm_bt<2><<<dim3(32, 8), 256, 0, stream>>>(ctxb, wot, x1, wo_b, x, 4096, 1024, 1024);
  ln_kernel<<<4096, 256, 0, stream>>>(x1, ln2g, ln2b, xn);
  gemm_bt<1><<<dim3(32, 32), 256, 0, stream>>>(xn, w1t, hbuf, b1, nullptr, 4096, 4096, 1024);
  gemm_bt<2><<<dim3(32, 8), 256, 0, stream>>>(hbuf, w2t, (float*)d_out, b2, x1, 4096, 1024, 4096);

  (void)in_sizes; (void)n_in; (void)out_size; (void)ws_size;
}

// Round 7
// 399.503 us; speedup vs baseline: 5.8016x; 1.0067x over previous
//
#include <hip/hip_runtime.h>
#include <hip/hip_bf16.h>
#include <stdint.h>

// ---------- types ----------
typedef unsigned short u16;
typedef __bf16 bf16x8 __attribute__((ext_vector_type(8)));
typedef u16   u16x8  __attribute__((ext_vector_type(8)));
typedef u16   u16x4  __attribute__((ext_vector_type(4)));
typedef u16   u16x2  __attribute__((ext_vector_type(2)));
typedef float f32x4  __attribute__((ext_vector_type(4)));

__device__ __forceinline__ u16 f2bf(float f) {
  union { float f; uint32_t u; } v; v.f = f;
  uint32_t r = v.u + 0x7fffu + ((v.u >> 16) & 1u);   // RNE
  return (u16)(r >> 16);
}

// async global->LDS, 16B per lane
typedef __attribute__((address_space(1))) void gvoid_t;
typedef __attribute__((address_space(3))) void lvoid_t;
__device__ __forceinline__ void gload_lds16(const void* g, void* l) {
  __builtin_amdgcn_global_load_lds((gvoid_t*)g, (lvoid_t*)l, 16, 0, 0);
}

// ---------- DPP row(16-lane) reductions — VALU pipe, no DS ----------
template<int CTRL>
__device__ __forceinline__ float dpp_f(float x) {
  int i = __builtin_bit_cast(int, x);
  i = __builtin_amdgcn_update_dpp(i, i, CTRL, 0xF, 0xF, true);
  return __builtin_bit_cast(float, i);
}
__device__ __forceinline__ float rowmax16(float x) {   // ROW_ROR 8,4,2,1
  x = fmaxf(x, dpp_f<0x128>(x));
  x = fmaxf(x, dpp_f<0x124>(x));
  x = fmaxf(x, dpp_f<0x122>(x));
  x = fmaxf(x, dpp_f<0x121>(x));
  return x;
}
__device__ __forceinline__ float rowsum16(float x) {
  x += dpp_f<0x128>(x);
  x += dpp_f<0x124>(x);
  x += dpp_f<0x122>(x);
  x += dpp_f<0x121>(x);
  return x;
}

// ---------- LayerNorm (f32 in -> bf16 out), 1024 cols, one row per block ----------
__global__ __launch_bounds__(256)
void ln_kernel(const float* __restrict__ x, const float* __restrict__ g,
               const float* __restrict__ b, u16* __restrict__ out) {
  const int row = blockIdx.x;
  const int tid = threadIdx.x;
  const float* xr = x + (size_t)row * 1024;
  f32x4 v = *(const f32x4*)&xr[tid * 4];
  float s = v[0] + v[1] + v[2] + v[3];
  float q = v[0]*v[0] + v[1]*v[1] + v[2]*v[2] + v[3]*v[3];
  #pragma unroll
  for (int o = 32; o > 0; o >>= 1) { s += __shfl_xor(s, o); q += __shfl_xor(q, o); }
  __shared__ float ss[4], qq[4];
  if ((tid & 63) == 0) { ss[tid >> 6] = s; qq[tid >> 6] = q; }
  __syncthreads();
  s = ss[0] + ss[1] + ss[2] + ss[3];
  q = qq[0] + qq[1] + qq[2] + qq[3];
  float mu = s * (1.0f / 1024.0f);
  float var = q * (1.0f / 1024.0f) - mu * mu;
  float rstd = rsqrtf(var + 1e-5f);
  u16x4 o4;
  #pragma unroll
  for (int i = 0; i < 4; ++i)
    o4[i] = f2bf((v[i] - mu) * rstd * g[tid * 4 + i] + b[tid * 4 + i]);
  *(u16x4*)&out[(size_t)row * 1024 + tid * 4] = o4;
}

// ---------- transpose + cast: W f32 [K][N] -> Wt bf16 [N][K] ----------
__global__ __launch_bounds__(256)
void transpose_cast(const float* __restrict__ W, u16* __restrict__ Wt, int K, int N) {
  __shared__ float t[32][33];
  const int n0 = blockIdx.x * 32, k0 = blockIdx.y * 32;
  const int tx = threadIdx.x & 31, ty = threadIdx.x >> 5;  // ty 0..7
  #pragma unroll
  for (int i = 0; i < 4; ++i)
    t[ty + 8*i][tx] = W[(size_t)(k0 + ty + 8*i) * N + n0 + tx];
  __syncthreads();
  #pragma unroll
  for (int i = 0; i < 4; ++i)
    Wt[(size_t)(n0 + ty + 8*i) * K + k0 + tx] = f2bf(t[tx][ty + 8*i]);
}

// ---------- GEMM: C[M][N] = A[M][K] @ Bt[N][K]^T  (both bf16, f32 accum) ----------
template<int EPI>
__global__ __launch_bounds__(256, 2)
void gemm_bt(const u16* __restrict__ A, const u16* __restrict__ Bt,
             void* __restrict__ out, const float* __restrict__ bias,
             const float* __restrict__ resid, int M, int N, int K) {
  __shared__ u16 As[128 * 32];
  __shared__ u16 Bs[128 * 32];
  const int tid = threadIdx.x;
  const int w = tid >> 6, l = tid & 63;
  const int bm = blockIdx.x * 128, bn = blockIdx.y * 128;
  const int wr = (w >> 1) * 64, wc = (w & 1) * 64;
  const int l15 = l & 15, lhi = l >> 4;
  f32x4 acc[4][4] = {};

  const int r4 = tid >> 2;
  const int c8 = (tid & 3) * 8;
  const u16* ga0 = A  + (size_t)(bm + r4) * K + c8;
  const u16* ga1 = ga0 + (size_t)64 * K;
  const u16* gb0 = Bt + (size_t)(bn + r4) * K + c8;
  const u16* gb1 = gb0 + (size_t)64 * K;
  u16* lA0 = &As[(w * 16) * 32];
  u16* lA1 = &As[(64 + w * 16) * 32];
  u16* lB0 = &Bs[(w * 16) * 32];
  u16* lB1 = &Bs[(64 + w * 16) * 32];

  const int arow = (wr + l15) * 32 + lhi * 8;
  const int brow = (wc + l15) * 32 + lhi * 8;

  for (int k0 = 0; k0 < K; k0 += 32) {
    gload_lds16(ga0 + k0, lA0);
    gload_lds16(ga1 + k0, lA1);
    gload_lds16(gb0 + k0, lB0);
    gload_lds16(gb1 + k0, lB1);
    __syncthreads();
    bf16x8 a[4], b[4];
    #pragma unroll
    for (int m = 0; m < 4; ++m) a[m] = *(const bf16x8*)&As[arow + m * 16 * 32];
    #pragma unroll
    for (int n = 0; n < 4; ++n) b[n] = *(const bf16x8*)&Bs[brow + n * 16 * 32];
    #pragma unroll
    for (int m = 0; m < 4; ++m)
      #pragma unroll
      for (int n = 0; n < 4; ++n)
        acc[m][n] = __builtin_amdgcn_mfma_f32_16x16x32_bf16(a[m], b[n], acc[m][n], 0, 0, 0);
    __syncthreads();
  }

  #pragma unroll
  for (int m = 0; m < 4; ++m) {
    #pragma unroll
    for (int n = 0; n < 4; ++n) {
      #pragma unroll
      for (int r = 0; r < 4; ++r) {
        const int grow = bm + wr + m * 16 + lhi * 4 + r;
        const int gcol = bn + wc + n * 16 + l15;
        float vv = acc[m][n][r];
        if constexpr (EPI >= 1) vv += bias[gcol];
        if constexpr (EPI == 1) vv = 0.5f * vv * (1.0f + erff(vv * 0.70710678118f));
        if constexpr (EPI == 2) {
          vv += resid[(size_t)grow * N + gcol];
          ((float*)out)[(size_t)grow * N + gcol] = vv;
        } else {
          ((u16*)out)[(size_t)grow * N + gcol] = f2bf(vv);
        }
      }
    }
  }
}

// ---------- fused flash attention v7 ----------
// Grid 32x32, 256 thr / 4 waves, one batch-head per block.
// K/V LDS DOUBLE-buffered -> ONE barrier per iter: {store regs->nxt;
// load it+2->regs; compute from cur; barrier; swap}. Bias via 4 row
// pointers (+64/iter, offsets fold to immediates). P->bf16 via compiler
// casts (v_cvt_pk_bf16_f32). DPP softmax (defer-max), XOR-swizzled LDS.
// qkv: bf16 [B*S][3072]; bias: f32 [H][S][S]; ctx: bf16 [B*S][1024]
#define SWZ(row) ((((row) & 7) ^ (((row) >> 3) & 7)) << 3)

__global__ __launch_bounds__(256)
void attn_kernel(const u16* __restrict__ qkv, const float* __restrict__ bias,
                 u16* __restrict__ ctx) {
  const int qt = blockIdx.x;            // 0..31 (64 q-rows)
  const int bh = blockIdx.y;            // 0..31
  const int b = bh >> 4, h = bh & 15;
  const int tid = threadIdx.x, w = tid >> 6, l = tid & 63;
  const int l15 = l & 15, lhi = l >> 4;
  const size_t ld = 3072;
  const float L2E = 1.44269504f;

  __shared__ u16 Kl[2][4096];           // dbuf [key][64] swizzled
  __shared__ u16 Vt[2][4096];           // dbuf [d][64] (V^T) swizzled
  __shared__ u16 Pl[4][1024];           // per wave [qrow16][64] swizzled

  const u16* qp = qkv;
  const u16* kp = qkv + 1024;
  const u16* vp = qkv + 2048;

  // staging shard: key2 = 2 consecutive keys, dg8 = 8 d-elems
  const int key2 = (tid >> 3) * 2, dg8 = (tid & 7) * 8;
  const u16* kbase = kp + ((size_t)b * 2048 + key2) * ld + h * 64 + dg8;
  const u16* vbase = vp + ((size_t)b * 2048 + key2) * ld + h * 64 + dg8;

  // Q fragments: 16 q-rows per wave
  bf16x8 qf0, qf1;
  {
    const u16* qrow = qp + ((size_t)b * 2048 + qt * 64 + w * 16 + l15) * ld + h * 64 + lhi * 8;
    qf0 = *(const bf16x8*)qrow;
    qf1 = *(const bf16x8*)(qrow + 32);
  }

  // bias row pointers, bumped +64 floats per loaded tile
  const float* bg0 = bias + ((size_t)h * 2048 + qt * 64 + w * 16 + lhi * 4) * 2048 + l15;
  const float* bp0 = bg0;
  const float* bp1 = bg0 + 2048;
  const float* bp2 = bg0 + 4096;
  const float* bp3 = bg0 + 6144;

  float m_run[4], s_run[4];
  f32x4 octx[4] = {};
  #pragma unroll
  for (int r = 0; r < 4; ++r) { m_run[r] = -1e30f; s_run[r] = 0.f; }

  u16x8 kpf[2], vpf[2];                 // K/V reg prefetch (single set)
  float bf[16];                         // bias regs (single set)

  auto load_kv = [&](int kv) {
    kpf[0] = *(const u16x8*)(kbase + (size_t)kv * ld);
    kpf[1] = *(const u16x8*)(kbase + (size_t)(kv + 1) * ld);
    vpf[0] = *(const u16x8*)(vbase + (size_t)kv * ld);
    vpf[1] = *(const u16x8*)(vbase + (size_t)(kv + 1) * ld);
  };
  auto load_bias = [&]() {              // reads current ptrs, then bumps
    bf[0]  = bp0[0];  bf[1]  = bp0[16]; bf[2]  = bp0[32]; bf[3]  = bp0[48];
    bf[4]  = bp1[0];  bf[5]  = bp1[16]; bf[6]  = bp1[32]; bf[7]  = bp1[48];
    bf[8]  = bp2[0];  bf[9]  = bp2[16]; bf[10] = bp2[32]; bf[11] = bp2[48];
    bf[12] = bp3[0];  bf[13] = bp3[16]; bf[14] = bp3[32]; bf[15] = bp3[48];
    bp0 += 64; bp1 += 64; bp2 += 64; bp3 += 64;
  };
  auto store_kv = [&](u16* Kd, u16* Vd) {
    *(u16x8*)&Kd[(key2)     * 64 + (dg8 ^ SWZ(key2))]     = kpf[0];
    *(u16x8*)&Kd[(key2 + 1) * 64 + (dg8 ^ SWZ(key2 + 1))] = kpf[1];
    #pragma unroll
    for (int i = 0; i < 8; ++i) {
      const int d = dg8 + i;
      u16x2 vq = { vpf[0][i], vpf[1][i] };
      *(u16x2*)&Vd[d * 64 + (key2 ^ SWZ(d))] = vq;
    }
  };

  // ---- prologue: tile 0 staged, tile 1 in regs, bias(0) in regs ----
  load_kv(0);
  load_bias();
  store_kv(Kl[0], Vt[0]);
  load_kv(64);
  __syncthreads();

  for (int it = 0; it < 32; ++it) {
    const int cur = it & 1, nxt = cur ^ 1;
    // store tile it+1 (regs, loaded last iter) into the other buffer
    if (it < 31) store_kv(Kl[nxt], Vt[nxt]);
    // refill regs with tile it+2
    if (it < 30) load_kv((it + 2) * 64);

    // ---- QK^T from cur ----
    f32x4 sa[4] = {};
    #pragma unroll
    for (int nf = 0; nf < 4; ++nf) {
      const int row = nf * 16 + l15;
      const int s = SWZ(row);
      bf16x8 kf0 = *(const bf16x8*)&Kl[cur][row * 64 + ((lhi * 8) ^ s)];
      bf16x8 kf1 = *(const bf16x8*)&Kl[cur][row * 64 + ((32 + lhi * 8) ^ s)];
      sa[nf] = __builtin_amdgcn_mfma_f32_16x16x32_bf16(qf0, kf0, sa[nf], 0, 0, 0);
      sa[nf] = __builtin_amdgcn_mfma_f32_16x16x32_bf16(qf1, kf1, sa[nf], 0, 0, 0);
    }

    // ---- consume bias, then immediately re-issue loads for it+1 ----
    float p[4][4];
    #pragma unroll
    for (int r = 0; r < 4; ++r)
      #pragma unroll
      for (int nf = 0; nf < 4; ++nf)
        p[r][nf] = fmaf(sa[nf][r], 0.125f, bf[r * 4 + nf]);
    if (it < 31) load_bias();           // full softmax+PV window to land

    // ---- softmax (defer-max, DPP reductions, exp2) ----
    #pragma unroll
    for (int r = 0; r < 4; ++r) {
      float mx = fmaxf(fmaxf(p[r][0], p[r][1]), fmaxf(p[r][2], p[r][3]));
      mx = rowmax16(mx);
      if (mx > m_run[r] + 5.545177f) {       // 8 in log2 units
        const float fs = exp2f((m_run[r] - mx) * L2E);
        s_run[r] *= fs;
        #pragma unroll
        for (int nf = 0; nf < 4; ++nf) octx[nf][r] *= fs;
        m_run[r] = mx;
      }
      const float nml = -m_run[r] * L2E;
      float e0 = exp2f(fmaf(p[r][0], L2E, nml));
      float e1 = exp2f(fmaf(p[r][1], L2E, nml));
      float e2 = exp2f(fmaf(p[r][2], L2E, nml));
      float e3 = exp2f(fmaf(p[r][3], L2E, nml));
      p[r][0] = e0; p[r][1] = e1; p[r][2] = e2; p[r][3] = e3;
      s_run[r] += rowsum16((e0 + e1) + (e2 + e3));
    }

    // ---- P -> per-wave LDS (hw cvt, same-wave ordering, no barrier) ----
    #pragma unroll
    for (int r = 0; r < 4; ++r) {
      const int row = lhi * 4 + r;
      const int s = SWZ(row);
      #pragma unroll
      for (int nf = 0; nf < 4; ++nf)
        Pl[w][row * 64 + ((nf * 16 + l15) ^ s)] =
            __builtin_bit_cast(u16, (__bf16)p[r][nf]);
    }

    // ---- PV from cur ----
    #pragma unroll
    for (int ks = 0; ks < 2; ++ks) {
      bf16x8 pa = *(const bf16x8*)&Pl[w][l15 * 64 + ((ks * 32 + lhi * 8) ^ SWZ(l15))];
      #pragma unroll
      for (int nf = 0; nf < 4; ++nf) {
        const int row = nf * 16 + l15;
        bf16x8 bv = *(const bf16x8*)&Vt[cur][row * 64 + ((ks * 32 + lhi * 8) ^ SWZ(row))];
        octx[nf] = __builtin_amdgcn_mfma_f32_16x16x32_bf16(pa, bv, octx[nf], 0, 0, 0);
      }
    }

    __syncthreads();   // cur fully read by all waves AND nxt fully written
  }

  // ---- normalize + write ctx ----
  float inv[4];
  #pragma unroll
  for (int r = 0; r < 4; ++r) inv[r] = 1.0f / s_run[r];
  #pragma unroll
  for (int nf = 0; nf < 4; ++nf)
    #pragma unroll
    for (int r = 0; r < 4; ++r) {
      const int grow = b * 2048 + qt * 64 + w * 16 + lhi * 4 + r;
      const int gcol = h * 64 + nf * 16 + l15;
      ctx[(size_t)grow * 1024 + gcol] = f2bf(octx[nf][r] * inv[r]);
    }
}

// ---------- launch ----------
extern "C" void kernel_launch(void* const* d_in, const int* in_sizes, int n_in,
                              void* d_out, int out_size, void* d_ws, size_t ws_size,
                              hipStream_t stream) {
  const float* x    = (const float*)d_in[0];
  const float* rb   = (const float*)d_in[1];
  const float* wq   = (const float*)d_in[2];
  const float* wk   = (const float*)d_in[3];
  const float* wv   = (const float*)d_in[4];
  const float* wo   = (const float*)d_in[5];
  const float* wo_b = (const float*)d_in[6];
  const float* w1   = (const float*)d_in[7];
  const float* b1   = (const float*)d_in[8];
  const float* w2   = (const float*)d_in[9];
  const float* b2   = (const float*)d_in[10];
  const float* ln1g = (const float*)d_in[11];
  const float* ln1b = (const float*)d_in[12];
  const float* ln2g = (const float*)d_in[13];
  const float* ln2b = (const float*)d_in[14];

  char* ws = (char*)d_ws;
  u16*   xn    = (u16*)(ws + 0);                    //  8 MB
  u16*   qkvb  = (u16*)(ws + (8u << 20));           // 24 MB
  u16*   hbuf  = (u16*)(ws + (8u << 20));           // 32 MB (reuses qkv+ctx)
  u16*   ctxb  = (u16*)(ws + (32u << 20));          //  8 MB
  float* x1    = (float*)(ws + (40u << 20));        // 16 MB
  u16*   wqkvt = (u16*)(ws + (56u << 20));          //  6 MB
  u16*   wot   = (u16*)(ws + (62u << 20));          //  2 MB
  u16*   w1t   = (u16*)(ws + (64u << 20));          //  8 MB
  u16*   w2t   = (u16*)(ws + (72u << 20));          //  8 MB

  transpose_cast<<<dim3(32, 32),  256, 0, stream>>>(wq, wqkvt,               1024, 1024);
  transpose_cast<<<dim3(32, 32),  256, 0, stream>>>(wk, wqkvt + 1024 * 1024, 1024, 1024);
  transpose_cast<<<dim3(32, 32),  256, 0, stream>>>(wv, wqkvt + 2048 * 1024, 1024, 1024);
  transpose_cast<<<dim3(32, 32),  256, 0, stream>>>(wo, wot,                 1024, 1024);
  transpose_cast<<<dim3(128, 32), 256, 0, stream>>>(w1, w1t,                 1024, 4096);
  transpose_cast<<<dim3(32, 128), 256, 0, stream>>>(w2, w2t,                 4096, 1024);

  ln_kernel<<<4096, 256, 0, stream>>>(x, ln1g, ln1b, xn);
  gemm_bt<0><<<dim3(32, 24), 256, 0, stream>>>(xn, wqkvt, qkvb, nullptr, nullptr, 4096, 3072, 1024);
  attn_kernel<<<dim3(32, 32), 256, 0, stream>>>(qkvb, rb, ctxb);
  gemm_bt<2><<<dim3(32, 8), 256, 0, stream>>>(ctxb, wot, x1, wo_b, x, 4096, 1024, 1024);
  ln_kernel<<<4096, 256, 0, stream>>>(x1, ln2g, ln2b, xn);
  gemm_bt<1><<<dim3(32, 32), 256, 0, stream>>>(xn, w1t, hbuf, b1, nullptr, 4096, 4096, 1024);
  gemm_bt<2><<<dim3(32, 8), 256, 0, stream>>>(hbuf, w2t, (float*)d_out, b2, x1, 4096, 1024, 4096);

  (void)in_sizes; (void)n_in; (void)out_size; (void)ws_size;
}